// Round 1
// baseline (522.886 us; speedup 1.0000x reference)
//
#include <hip/hip_runtime.h>

// Atom_embedding_MP: B=4, N=100000, K=16, D=6, C_IN=13, 3 layers.
// One thread per point. Algebraic reductions:
//   - base[d] = b1[d] + pe@W1[0:6,:]  hoisted out of the neighbor loop
//   - second matmul applied to sum of lrelu(h_k)  (linear), b2 scaled by 16
// Weights read via wave-uniform addresses -> scalar loads (SGPR operands).

constexpr int DD  = 6;
constexpr int KK  = 16;
constexpr int CIN = 13;
constexpr float EPSV  = 1e-5f;
constexpr float SLOPE = 0.2f;

__device__ __forceinline__ float lrelu(float x) {
    return x >= 0.f ? x : SLOPE * x;
}

__global__ __launch_bounds__(256) void atom_mp(
    const float* __restrict__ dist,   // [P, K]
    const float* __restrict__ at,     // [P, K, D]
    const float* __restrict__ W1,     // [3, CIN, CIN]
    const float* __restrict__ b1,     // [3, CIN]
    const float* __restrict__ W2,     // [3, CIN, D]
    const float* __restrict__ b2,     // [3, D]
    const float* __restrict__ gw,     // [3, D]
    const float* __restrict__ gb,     // [3, D]
    float* __restrict__ out,          // [P, D]
    int P)
{
    int p = blockIdx.x * blockDim.x + threadIdx.x;
    if (p >= P) return;

    float pe[DD] = {1.f, 1.f, 1.f, 1.f, 1.f, 1.f};

    const float* atp = at + (long)p * (KK * DD);
    const float* dp  = dist + (long)p * KK;

    #pragma unroll 1
    for (int L = 0; L < 3; ++L) {
        const float* w1  = W1 + L * CIN * CIN;
        const float* w2  = W2 + L * CIN * DD;
        const float* bb1 = b1 + L * CIN;
        const float* bb2 = b2 + L * DD;
        const float* gwp = gw + L * DD;
        const float* gbp = gb + L * DD;

        // base[d] = b1[d] + sum_{c<6} pe[c] * W1[c][d]
        float base[CIN];
        #pragma unroll
        for (int d = 0; d < CIN; ++d) {
            float s = bb1[d];
            #pragma unroll
            for (int c = 0; c < DD; ++c)
                s = fmaf(pe[c], w1[c * CIN + d], s);
            base[d] = s;
        }

        float hsum[CIN];
        #pragma unroll
        for (int d = 0; d < CIN; ++d) hsum[d] = 0.f;

        // neighbors in pairs: 12 atom floats = 3 aligned float4
        for (int kp = 0; kp < KK / 2; ++kp) {
            float4 q0 = *reinterpret_cast<const float4*>(atp + kp * 12);
            float4 q1 = *reinterpret_cast<const float4*>(atp + kp * 12 + 4);
            float4 q2 = *reinterpret_cast<const float4*>(atp + kp * 12 + 8);
            float2 dq = *reinterpret_cast<const float2*>(dp + kp * 2);

            float f0[7] = {q0.x, q0.y, q0.z, q0.w, q1.x, q1.y, dq.x};
            float f1[7] = {q1.z, q1.w, q2.x, q2.y, q2.z, q2.w, dq.y};

            #pragma unroll
            for (int d = 0; d < CIN; ++d) {
                float a0 = base[d];
                float a1 = base[d];
                #pragma unroll
                for (int j = 0; j < 7; ++j) {
                    float w = w1[(6 + j) * CIN + d];
                    a0 = fmaf(f0[j], w, a0);
                    a1 = fmaf(f1[j], w, a1);
                }
                hsum[d] += lrelu(a0) + lrelu(a1);
            }
        }

        // msg = hsum @ W2 + 16*b2
        float msg[DD];
        #pragma unroll
        for (int d = 0; d < DD; ++d) {
            float m = 16.f * bb2[d];
            #pragma unroll
            for (int c = 0; c < CIN; ++c)
                m = fmaf(hsum[c], w2[c * DD + d], m);
            msg[d] = m;
        }

        // GroupNorm(2 groups of 3) + affine + lrelu, residual add
        #pragma unroll
        for (int g = 0; g < 2; ++g) {
            float m0 = msg[3 * g], m1 = msg[3 * g + 1], m2 = msg[3 * g + 2];
            float mu = (m0 + m1 + m2) * (1.f / 3.f);
            float d0 = m0 - mu, d1 = m1 - mu, d2 = m2 - mu;
            float var = (d0 * d0 + d1 * d1 + d2 * d2) * (1.f / 3.f);
            float rs = rsqrtf(var + EPSV);
            float dv[3] = {d0, d1, d2};
            #pragma unroll
            for (int c = 0; c < 3; ++c) {
                int ch = 3 * g + c;
                float xn = dv[c] * rs * gwp[ch] + gbp[ch];
                pe[ch] += lrelu(xn);
            }
        }
    }

    float2* op = reinterpret_cast<float2*>(out + (long)p * DD);
    op[0] = make_float2(pe[0], pe[1]);
    op[1] = make_float2(pe[2], pe[3]);
    op[2] = make_float2(pe[4], pe[5]);
}

extern "C" void kernel_launch(void* const* d_in, const int* in_sizes, int n_in,
                              void* d_out, int out_size, void* d_ws, size_t ws_size,
                              hipStream_t stream) {
    const float* dist = (const float*)d_in[0];
    const float* at   = (const float*)d_in[1];
    const float* W1   = (const float*)d_in[2];
    const float* b1   = (const float*)d_in[3];
    const float* W2   = (const float*)d_in[4];
    const float* b2   = (const float*)d_in[5];
    const float* gw   = (const float*)d_in[6];
    const float* gb   = (const float*)d_in[7];
    float* out = (float*)d_out;

    int P = in_sizes[0] / KK;  // dist is [P, K]
    int threads = 256;
    int blocks = (P + threads - 1) / threads;
    atom_mp<<<blocks, threads, 0, stream>>>(dist, at, W1, b1, W2, b2, gw, gb, out, P);
}

// Round 2
// 282.930 us; speedup vs baseline: 1.8481x; 1.8481x over previous
//
#include <hip/hip_runtime.h>

// Atom_embedding_MP: B=4, N=100000, K=16, D=6, C_IN=13, 3 layers.
// One thread per point. Round-2 change: load all 112 input floats (96
// atomtypes + 16 dist) into registers ONCE and run all 3 layers from
// registers — Round 1 re-read HBM per layer (FETCH 1.13 GB vs 180 MB
// footprint) and was fetch-bound at 3.3 TB/s.
// Algebraic reductions (from R1):
//   - base[d] = b1[d] + pe@W1[0:6,:] hoisted out of the neighbor loop
//   - second matmul applied to sum of lrelu(h_k) (linear), b2 scaled by 16
//   - lrelu(x) = max(x, 0.2x)  (valid since slope<1)

constexpr int DD  = 6;
constexpr int KK  = 16;
constexpr int CIN = 13;
constexpr float EPSV  = 1e-5f;
constexpr float SLOPE = 0.2f;

__global__ __launch_bounds__(256) void atom_mp(
    const float* __restrict__ dist,   // [P, K]
    const float* __restrict__ at,     // [P, K, D]
    const float* __restrict__ W1,     // [3, CIN, CIN]
    const float* __restrict__ b1,     // [3, CIN]
    const float* __restrict__ W2,     // [3, CIN, D]
    const float* __restrict__ b2,     // [3, D]
    const float* __restrict__ gw,     // [3, D]
    const float* __restrict__ gb,     // [3, D]
    float* __restrict__ out,          // [P, D]
    int P)
{
    int p = blockIdx.x * blockDim.x + threadIdx.x;
    if (p >= P) return;

    // ---- load the point's entire input into registers (one HBM pass) ----
    float a[KK * DD];   // 96 atom features
    float dd[KK];       // 16 distances

    const float4* ap4 = reinterpret_cast<const float4*>(at + (long)p * (KK * DD));
    #pragma unroll
    for (int i = 0; i < (KK * DD) / 4; ++i) {   // 24 x float4
        float4 q = ap4[i];
        a[4 * i + 0] = q.x; a[4 * i + 1] = q.y;
        a[4 * i + 2] = q.z; a[4 * i + 3] = q.w;
    }
    const float4* dp4 = reinterpret_cast<const float4*>(dist + (long)p * KK);
    #pragma unroll
    for (int i = 0; i < KK / 4; ++i) {          // 4 x float4
        float4 q = dp4[i];
        dd[4 * i + 0] = q.x; dd[4 * i + 1] = q.y;
        dd[4 * i + 2] = q.z; dd[4 * i + 3] = q.w;
    }

    float pe[DD] = {1.f, 1.f, 1.f, 1.f, 1.f, 1.f};

    #pragma unroll 1   // keep body ~2.3k instrs; fully unrolled would thrash I$
    for (int L = 0; L < 3; ++L) {
        const float* w1  = W1 + L * CIN * CIN;
        const float* w2  = W2 + L * CIN * DD;
        const float* bb1 = b1 + L * CIN;
        const float* bb2 = b2 + L * DD;
        const float* gwp = gw + L * DD;
        const float* gbp = gb + L * DD;

        // base[d] = b1[d] + sum_{c<6} pe[c] * W1[c][d]
        float base[CIN];
        #pragma unroll
        for (int d = 0; d < CIN; ++d) {
            float s = bb1[d];
            #pragma unroll
            for (int c = 0; c < DD; ++c)
                s = fmaf(pe[c], w1[c * CIN + d], s);
            base[d] = s;
        }

        float hsum[CIN];
        #pragma unroll
        for (int d = 0; d < CIN; ++d) hsum[d] = 0.f;

        #pragma unroll
        for (int k = 0; k < KK; ++k) {
            float f[7] = {a[6 * k + 0], a[6 * k + 1], a[6 * k + 2],
                          a[6 * k + 3], a[6 * k + 4], a[6 * k + 5], dd[k]};
            #pragma unroll
            for (int d = 0; d < CIN; ++d) {
                float acc = base[d];
                #pragma unroll
                for (int j = 0; j < 7; ++j)
                    acc = fmaf(f[j], w1[(6 + j) * CIN + d], acc);
                // lrelu(x) = max(x, 0.2x) since slope < 1
                hsum[d] += fmaxf(acc, SLOPE * acc);
            }
        }

        // msg = hsum @ W2 + 16*b2
        float msg[DD];
        #pragma unroll
        for (int d = 0; d < DD; ++d) {
            float m = 16.f * bb2[d];
            #pragma unroll
            for (int c = 0; c < CIN; ++c)
                m = fmaf(hsum[c], w2[c * DD + d], m);
            msg[d] = m;
        }

        // GroupNorm(2 groups of 3) + affine + lrelu, residual add
        #pragma unroll
        for (int g = 0; g < 2; ++g) {
            float m0 = msg[3 * g], m1 = msg[3 * g + 1], m2 = msg[3 * g + 2];
            float mu = (m0 + m1 + m2) * (1.f / 3.f);
            float d0 = m0 - mu, d1 = m1 - mu, d2 = m2 - mu;
            float var = (d0 * d0 + d1 * d1 + d2 * d2) * (1.f / 3.f);
            float rs = rsqrtf(var + EPSV);
            float dv[3] = {d0, d1, d2};
            #pragma unroll
            for (int c = 0; c < 3; ++c) {
                int ch = 3 * g + c;
                float xn = dv[c] * rs * gwp[ch] + gbp[ch];
                pe[ch] += fmaxf(xn, SLOPE * xn);
            }
        }
    }

    float2* op = reinterpret_cast<float2*>(out + (long)p * DD);
    op[0] = make_float2(pe[0], pe[1]);
    op[1] = make_float2(pe[2], pe[3]);
    op[2] = make_float2(pe[4], pe[5]);
}

extern "C" void kernel_launch(void* const* d_in, const int* in_sizes, int n_in,
                              void* d_out, int out_size, void* d_ws, size_t ws_size,
                              hipStream_t stream) {
    const float* dist = (const float*)d_in[0];
    const float* at   = (const float*)d_in[1];
    const float* W1   = (const float*)d_in[2];
    const float* b1   = (const float*)d_in[3];
    const float* W2   = (const float*)d_in[4];
    const float* b2   = (const float*)d_in[5];
    const float* gw   = (const float*)d_in[6];
    const float* gb   = (const float*)d_in[7];
    float* out = (float*)d_out;

    int P = in_sizes[0] / KK;  // dist is [P, K]
    int threads = 256;
    int blocks = (P + threads - 1) / threads;
    atom_mp<<<blocks, threads, 0, stream>>>(dist, at, W1, b1, W2, b2, gw, gb, out, P);
}

// Round 3
// 272.696 us; speedup vs baseline: 1.9175x; 1.0375x over previous
//
#include <hip/hip_runtime.h>

// Atom_embedding_MP: B=4, N=100000, K=16, D=6, C_IN=13, 3 layers.
// Round-3: TWO threads per point (8 neighbors each).
//  - 56 input floats/thread stay register-resident across all 3 layers
//    (R2's 112/thread got sunk back into the layer loop by the compiler:
//     VGPR_Count was only 80 -> per-layer L2/L3 re-reads + latency stalls).
//  - 2x wave count (12.5k waves) to hide scalar/vector load latency.
//  - loop order d->j->k: each W1 weight s_loaded once/layer, reused over 8 k.
//  - lrelu-acc:  sum += max(x,.2x)  ==  sum += .6x + .4|x|  (2 FMAs, free abs).
//  - hsum[13] pair-reduced with __shfl_xor(.,1); tail (msg/GN/pe) done
//    redundantly in both lanes (no divergence, no broadcast).

constexpr int DD  = 6;
constexpr int KK  = 16;
constexpr int CIN = 13;
constexpr float EPSV = 1e-5f;

__global__ __launch_bounds__(256) void atom_mp(
    const float* __restrict__ dist,   // [P, K]
    const float* __restrict__ at,     // [P, K, D]
    const float* __restrict__ W1,     // [3, CIN, CIN]
    const float* __restrict__ b1,     // [3, CIN]
    const float* __restrict__ W2,     // [3, CIN, D]
    const float* __restrict__ b2,     // [3, D]
    const float* __restrict__ gw,     // [3, D]
    const float* __restrict__ gb,     // [3, D]
    float* __restrict__ out,          // [P, D]
    int P)
{
    int t = blockIdx.x * blockDim.x + threadIdx.x;
    int p = t >> 1;      // point index
    int h = t & 1;       // which half of the neighbors
    if (p >= P) return;

    // ---- register-resident input: 8 neighbors x 6 feats + 8 dists --------
    float a[8 * DD];   // 48 floats
    float dq[8];

    const float4* ap4 = reinterpret_cast<const float4*>(
        at + (long)p * (KK * DD) + h * (8 * DD));
    #pragma unroll
    for (int i = 0; i < 12; ++i) {
        float4 q = ap4[i];
        a[4 * i + 0] = q.x; a[4 * i + 1] = q.y;
        a[4 * i + 2] = q.z; a[4 * i + 3] = q.w;
    }
    const float4* dp4 = reinterpret_cast<const float4*>(
        dist + (long)p * KK + h * 8);
    #pragma unroll
    for (int i = 0; i < 2; ++i) {
        float4 q = dp4[i];
        dq[4 * i + 0] = q.x; dq[4 * i + 1] = q.y;
        dq[4 * i + 2] = q.z; dq[4 * i + 3] = q.w;
    }

    float pe[DD] = {1.f, 1.f, 1.f, 1.f, 1.f, 1.f};

    #pragma unroll 1   // keep body in I$; each layer body ~1.2k instrs
    for (int L = 0; L < 3; ++L) {
        const float* w1  = W1 + L * CIN * CIN;
        const float* w2  = W2 + L * CIN * DD;
        const float* bb1 = b1 + L * CIN;
        const float* bb2 = b2 + L * DD;
        const float* gwp = gw + L * DD;
        const float* gbp = gb + L * DD;

        float hsum[CIN];

        #pragma unroll
        for (int d = 0; d < CIN; ++d) {
            // base_d = b1[d] + pe @ W1[0:6, d]
            float s = bb1[d];
            #pragma unroll
            for (int c = 0; c < DD; ++c)
                s = fmaf(pe[c], w1[c * CIN + d], s);

            // acc[k] over 8 neighbors; init folded into the j=0 FMA
            float w0 = w1[6 * CIN + d];
            float acc[8];
            #pragma unroll
            for (int k = 0; k < 8; ++k)
                acc[k] = fmaf(a[6 * k + 0], w0, s);
            #pragma unroll
            for (int j = 1; j < 7; ++j) {
                float w = w1[(6 + j) * CIN + d];
                #pragma unroll
                for (int k = 0; k < 8; ++k) {
                    float fv = (j < 6) ? a[6 * k + j] : dq[k];
                    acc[k] = fmaf(fv, w, acc[k]);
                }
            }
            // sum_k lrelu(acc[k]) = sum_k 0.6*acc + 0.4*|acc|
            float hs = 0.f;
            #pragma unroll
            for (int k = 0; k < 8; ++k) {
                hs = fmaf(0.6f, acc[k], hs);
                hs = fmaf(0.4f, __builtin_fabsf(acc[k]), hs);
            }
            hsum[d] = hs;
        }

        // reduce the lane pair (lanes 2i, 2i+1 hold halves of point i)
        #pragma unroll
        for (int d = 0; d < CIN; ++d)
            hsum[d] += __shfl_xor(hsum[d], 1, 64);

        // msg = hsum @ W2 + 16*b2   (both lanes, redundantly)
        float msg[DD];
        #pragma unroll
        for (int d = 0; d < DD; ++d) {
            float m = 16.f * bb2[d];
            #pragma unroll
            for (int c = 0; c < CIN; ++c)
                m = fmaf(hsum[c], w2[c * DD + d], m);
            msg[d] = m;
        }

        // GroupNorm(2 groups of 3) + affine + lrelu, residual add
        #pragma unroll
        for (int g = 0; g < 2; ++g) {
            float m0 = msg[3 * g], m1 = msg[3 * g + 1], m2 = msg[3 * g + 2];
            float mu = (m0 + m1 + m2) * (1.f / 3.f);
            float d0 = m0 - mu, d1 = m1 - mu, d2 = m2 - mu;
            float var = (d0 * d0 + d1 * d1 + d2 * d2) * (1.f / 3.f);
            float rs = rsqrtf(var + EPSV);
            float dv[3] = {d0, d1, d2};
            #pragma unroll
            for (int c = 0; c < 3; ++c) {
                int ch = 3 * g + c;
                float xn = fmaf(dv[c] * rs, gwp[ch], gbp[ch]);
                pe[ch] = fmaf(0.6f, xn, pe[ch]);
                pe[ch] = fmaf(0.4f, __builtin_fabsf(xn), pe[ch]);
            }
        }
    }

    // both lanes hold identical pe; split the 6-float store across the pair
    float* op = out + (long)p * DD;
    if (h == 0) {
        *reinterpret_cast<float2*>(op)     = make_float2(pe[0], pe[1]);
        *reinterpret_cast<float2*>(op + 2) = make_float2(pe[2], pe[3]);
    } else {
        *reinterpret_cast<float2*>(op + 4) = make_float2(pe[4], pe[5]);
    }
}

extern "C" void kernel_launch(void* const* d_in, const int* in_sizes, int n_in,
                              void* d_out, int out_size, void* d_ws, size_t ws_size,
                              hipStream_t stream) {
    const float* dist = (const float*)d_in[0];
    const float* at   = (const float*)d_in[1];
    const float* W1   = (const float*)d_in[2];
    const float* b1   = (const float*)d_in[3];
    const float* W2   = (const float*)d_in[4];
    const float* b2   = (const float*)d_in[5];
    const float* gw   = (const float*)d_in[6];
    const float* gb   = (const float*)d_in[7];
    float* out = (float*)d_out;

    int P = in_sizes[0] / KK;   // dist is [P, K]
    long threads_total = 2L * P;
    int threads = 256;
    int blocks = (int)((threads_total + threads - 1) / threads);
    atom_mp<<<blocks, threads, 0, stream>>>(dist, at, W1, b1, W2, b2, gw, gb, out, P);
}